// Round 1
// baseline (170.883 us; speedup 1.0000x reference)
//
#include <hip/hip_runtime.h>
#include <math.h>

#define NTOK 4096
#define NCH  256
#define EPS_F 1e-6f

// ---- workspace layout (float offsets) ----
#define OFF_WCQ 0
#define OFF_WCK (OFF_WCQ + 65536)
#define OFF_WCV (OFF_WCK + 65536)
#define OFF_BQ  (OFF_WCV + 65536)
#define OFF_BK  (OFF_BQ + 256)
#define OFF_BV  (OFF_BK + 256)
#define OFF_VC  (OFF_BV + 256)                 // conv output [256][4096]
#define OFF_QF  (OFF_VC + NCH*NTOK)            // [8][4096][64]
#define OFF_KF  (OFF_QF + 8*NTOK*64)
#define OFF_VF  (OFF_KF + 8*NTOK*64)
#define OFF_PS  (OFF_VF + 8*NTOK*64)           // partial Sm [8*16][64][64]
#define OFF_PSV (OFF_PS + 128*64*64)           // partial sv [8*16][64]
#define OFF_SM  (OFF_PSV + 128*64)             // Sm [8][64][64]
#define OFF_SV  (OFF_SM + 8*64*64)             // sv [8][64]

// Fold hedgehog linear into the 1x1x1 conv weights:
//   Wcq[h*64+e, c] = sum_d Wmq[e,d] * Wq[h*64+d, c]   (same for k)
//   Wcv[h*64+e, c] = block-diag expansion of Wmv; bv folded into effective bias.
__global__ __launch_bounds__(256) void k_combine(
    const float* __restrict__ Wq, const float* __restrict__ Wk,
    const float* __restrict__ Wmq, const float* __restrict__ bmq,
    const float* __restrict__ Wmk, const float* __restrict__ bmk,
    const float* __restrict__ Wmv, const float* __restrict__ bmv,
    const float* __restrict__ bv, float* __restrict__ ws)
{
    int row = blockIdx.x;        // 0..255 (h*64+e)
    int c = threadIdx.x;         // 0..255
    int h = row >> 6, e = row & 63;
    float aq = 0.f, ak = 0.f;
    for (int d = 0; d < 64; ++d) {
        float mq = Wmq[e*64 + d];
        float mk = Wmk[e*64 + d];
        int src = (h*64 + d)*256 + c;
        aq = fmaf(mq, Wq[src], aq);
        ak = fmaf(mk, Wk[src], ak);
    }
    ws[OFF_WCQ + row*256 + c] = aq;
    ws[OFF_WCK + row*256 + c] = ak;
    ws[OFF_WCV + row*256 + c] = ((c >> 6) == h) ? Wmv[e*64 + (c & 63)] : 0.f;
    if (c == 0) {
        float av = 0.f;
        for (int d = 0; d < 64; ++d) av = fmaf(Wmv[e*64 + d], bv[h*64 + d], av);
        ws[OFF_BV + row] = av + bmv[e];
        ws[OFF_BQ + row] = bmq[e];
        ws[OFF_BK + row] = bmk[e];
    }
}

// depthwise 3x3x3 conv, zero pad, NO bias (bias folded downstream)
__global__ __launch_bounds__(256) void k_dwconv(
    const float* __restrict__ x, const float* __restrict__ Wv, float* __restrict__ vc)
{
    int c = blockIdx.y;
    int n = blockIdx.x * 256 + threadIdx.x;
    int z = n >> 8, y = (n >> 4) & 15, xx = n & 15;
    const float* xc = x + c * 4096;
    const float* wc = Wv + c * 27;
    float acc = 0.f;
    #pragma unroll
    for (int kz = 0; kz < 3; ++kz) {
        int zz = z + kz - 1;
        if (zz < 0 || zz > 15) continue;
        #pragma unroll
        for (int ky = 0; ky < 3; ++ky) {
            int yy = y + ky - 1;
            if (yy < 0 || yy > 15) continue;
            #pragma unroll
            for (int kx = 0; kx < 3; ++kx) {
                int xv = xx + kx - 1;
                if (xv < 0 || xv > 15) continue;
                acc = fmaf(wc[(kz*3 + ky)*3 + kx], xc[(zz << 8) + (yy << 4) + xv], acc);
            }
        }
    }
    vc[c*4096 + n] = acc;
}

// C[256 rows][4096 tok] = Wc @ X, then write exp(+a) to head h, exp(-a) to head h+4
// out layout: [8 heads][4096 tok][64 e]
__global__ __launch_bounds__(256) void k_gemm_exp(
    const float* __restrict__ X, const float* __restrict__ Wc,
    const float* __restrict__ bias, float* __restrict__ outF)
{
    __shared__ float Xs[64][64];
    __shared__ float Ws[64][68];   // +4 pad: 16B-aligned rows, bounded write conflicts
    int t = threadIdx.x;
    int h = blockIdx.y;            // row tile == head (64 rows)
    int n0 = blockIdx.x * 64;
    int e4 = (t & 15) * 4;
    int n4 = (t >> 4) * 4;
    float acc[4][4];               // [token][e]
    #pragma unroll
    for (int i = 0; i < 4; ++i)
        #pragma unroll
        for (int j = 0; j < 4; ++j) acc[i][j] = 0.f;

    int lc = t >> 6;      // 0..3
    int ln = t & 63;
    for (int c0 = 0; c0 < 256; c0 += 64) {
        #pragma unroll
        for (int i = 0; i < 16; ++i) {
            int c = lc*16 + i;
            Xs[c][ln] = X[(c0 + c)*4096 + n0 + ln];
        }
        #pragma unroll
        for (int i = 0; i < 16; ++i) {
            int e = lc*16 + i;
            Ws[ln][e] = Wc[(h*64 + e)*256 + c0 + ln];
        }
        __syncthreads();
        #pragma unroll 4
        for (int c = 0; c < 64; ++c) {
            float4 xv4 = *(const float4*)&Xs[c][n4];
            float4 wv4 = *(const float4*)&Ws[c][e4];
            float xv[4] = {xv4.x, xv4.y, xv4.z, xv4.w};
            float wv[4] = {wv4.x, wv4.y, wv4.z, wv4.w};
            #pragma unroll
            for (int ii = 0; ii < 4; ++ii)
                #pragma unroll
                for (int jj = 0; jj < 4; ++jj)
                    acc[ii][jj] = fmaf(xv[ii], wv[jj], acc[ii][jj]);
        }
        __syncthreads();
    }
    float4 b4 = *(const float4*)&bias[h*64 + e4];
    float b[4] = {b4.x, b4.y, b4.z, b4.w};
    #pragma unroll
    for (int ii = 0; ii < 4; ++ii) {
        int n = n0 + n4 + ii;
        float pv[4], mv[4];
        #pragma unroll
        for (int jj = 0; jj < 4; ++jj) {
            float a = acc[ii][jj] + b[jj];
            pv[jj] = __expf(a);
            mv[jj] = __expf(-a);
        }
        *(float4*)&outF[((size_t)h*4096 + n)*64 + e4]     = make_float4(pv[0], pv[1], pv[2], pv[3]);
        *(float4*)&outF[((size_t)(h+4)*4096 + n)*64 + e4] = make_float4(mv[0], mv[1], mv[2], mv[3]);
    }
}

// per head: partial Sm[a][b] = sum_n kf[n,a]*vf[n,b]; partial sv[a] = sum_n kf[n,a]
__global__ __launch_bounds__(256) void k_kv_outer(float* __restrict__ ws)
{
    __shared__ float kfs[32][64];
    __shared__ float vfs[32][64];
    int t = threadIdx.x;
    int chunk = blockIdx.x;   // 0..15 (256 tokens each)
    int h = blockIdx.y;       // 0..7
    const float* kf = ws + OFF_KF + ((size_t)h*4096 + chunk*256) * 64;
    const float* vf = ws + OFF_VF + ((size_t)h*4096 + chunk*256) * 64;
    int a4 = (t & 15) * 4;
    int f4 = (t >> 4) * 4;
    float acc[4][4];
    #pragma unroll
    for (int i = 0; i < 4; ++i)
        #pragma unroll
        for (int j = 0; j < 4; ++j) acc[i][j] = 0.f;
    float sacc[4] = {0.f, 0.f, 0.f, 0.f};

    for (int b = 0; b < 8; ++b) {
        #pragma unroll
        for (int i = 0; i < 8; ++i) {
            int idx = i*256 + t;
            kfs[idx >> 6][idx & 63] = kf[b*2048 + idx];
            vfs[idx >> 6][idx & 63] = vf[b*2048 + idx];
        }
        __syncthreads();
        #pragma unroll 4
        for (int n = 0; n < 32; ++n) {
            float4 kv4 = *(const float4*)&kfs[n][a4];
            float4 vv4 = *(const float4*)&vfs[n][f4];
            float kv[4] = {kv4.x, kv4.y, kv4.z, kv4.w};
            float vv[4] = {vv4.x, vv4.y, vv4.z, vv4.w};
            #pragma unroll
            for (int ai = 0; ai < 4; ++ai) {
                sacc[ai] += kv[ai];
                #pragma unroll
                for (int fi = 0; fi < 4; ++fi)
                    acc[ai][fi] = fmaf(kv[ai], vv[fi], acc[ai][fi]);
            }
        }
        __syncthreads();
    }
    float* pS = ws + OFF_PS + ((size_t)(h*16 + chunk))*4096;
    #pragma unroll
    for (int ai = 0; ai < 4; ++ai)
        *(float4*)&pS[(a4 + ai)*64 + f4] = make_float4(acc[ai][0], acc[ai][1], acc[ai][2], acc[ai][3]);
    if ((t >> 4) == 0) {
        float* pv = ws + OFF_PSV + (size_t)(h*16 + chunk)*64;
        *(float4*)&pv[a4] = make_float4(sacc[0], sacc[1], sacc[2], sacc[3]);
    }
}

__global__ __launch_bounds__(256) void k_reduce(float* __restrict__ ws)
{
    int idx = blockIdx.x*256 + threadIdx.x;
    if (idx < 8*64*64) {
        int h = idx >> 12, r = idx & 4095;
        float s = 0.f;
        #pragma unroll
        for (int c = 0; c < 16; ++c) s += ws[OFF_PS + (size_t)(h*16 + c)*4096 + r];
        ws[OFF_SM + idx] = s;
    } else if (idx < 8*64*64 + 8*64) {
        int j = idx - 8*64*64;
        int h = j >> 6, e = j & 63;
        float s = 0.f;
        #pragma unroll
        for (int c = 0; c < 16; ++c) s += ws[OFF_PSV + (size_t)(h*16 + c)*64 + e];
        ws[OFF_SV + j] = s;
    }
}

// out[h*64+e][n] = (sum_a qf[n,a]*Sm[a][e]) / (sum_a qf[n,a]*sv[a] + EPS)
__global__ __launch_bounds__(256) void k_out(const float* __restrict__ ws, float* __restrict__ out)
{
    __shared__ float Sms[64][64];
    __shared__ float qfs[64][65];  // +1 pad: conflict-free column reads
    __shared__ float svs[64];
    int t = threadIdx.x;
    int h = blockIdx.y;
    int n0 = blockIdx.x * 64;
    const float* Sm = ws + OFF_SM + (size_t)h*4096;
    const float* qf = ws + OFF_QF + ((size_t)h*4096 + n0)*64;
    #pragma unroll
    for (int i = 0; i < 16; ++i) {
        int idx = i*256 + t;
        Sms[idx >> 6][idx & 63] = Sm[idx];
        qfs[idx >> 6][idx & 63] = qf[idx];
    }
    if (t < 64) svs[t] = ws[OFF_SV + h*64 + t];
    __syncthreads();

    int n4 = (t & 15) * 4;
    int e4 = (t >> 4) * 4;
    float acc[4][4];               // [e][n]
    #pragma unroll
    for (int i = 0; i < 4; ++i)
        #pragma unroll
        for (int j = 0; j < 4; ++j) acc[i][j] = 0.f;
    float den[4] = {0.f, 0.f, 0.f, 0.f};

    #pragma unroll 8
    for (int a = 0; a < 64; ++a) {
        float4 sm4 = *(const float4*)&Sms[a][e4];
        float sm[4] = {sm4.x, sm4.y, sm4.z, sm4.w};
        float qv[4];
        #pragma unroll
        for (int nj = 0; nj < 4; ++nj) qv[nj] = qfs[n4 + nj][a];
        float sv = svs[a];
        #pragma unroll
        for (int nj = 0; nj < 4; ++nj) {
            den[nj] = fmaf(qv[nj], sv, den[nj]);
            #pragma unroll
            for (int ei = 0; ei < 4; ++ei)
                acc[ei][nj] = fmaf(sm[ei], qv[nj], acc[ei][nj]);
        }
    }
    float r[4];
    #pragma unroll
    for (int nj = 0; nj < 4; ++nj) r[nj] = 1.f / (den[nj] + EPS_F);
    #pragma unroll
    for (int ei = 0; ei < 4; ++ei) {
        *(float4*)&out[(size_t)(h*64 + e4 + ei)*4096 + n0 + n4] =
            make_float4(acc[ei][0]*r[0], acc[ei][1]*r[1], acc[ei][2]*r[2], acc[ei][3]*r[3]);
    }
}

extern "C" void kernel_launch(void* const* d_in, const int* in_sizes, int n_in,
                              void* d_out, int out_size, void* d_ws, size_t ws_size,
                              hipStream_t stream) {
    const float* x   = (const float*)d_in[0];
    const float* Wq  = (const float*)d_in[1];
    const float* Wk  = (const float*)d_in[2];
    const float* Wv  = (const float*)d_in[3];
    const float* bv  = (const float*)d_in[4];
    const float* Wmq = (const float*)d_in[5];
    const float* bmq = (const float*)d_in[6];
    const float* Wmk = (const float*)d_in[7];
    const float* bmk = (const float*)d_in[8];
    const float* Wmv = (const float*)d_in[9];
    const float* bmv = (const float*)d_in[10];
    float* out = (float*)d_out;
    float* ws  = (float*)d_ws;

    k_combine<<<256, 256, 0, stream>>>(Wq, Wk, Wmq, bmq, Wmk, bmk, Wmv, bmv, bv, ws);
    k_dwconv<<<dim3(16, 256), 256, 0, stream>>>(x, Wv, ws + OFF_VC);
    k_gemm_exp<<<dim3(64, 4), 256, 0, stream>>>(x,            ws + OFF_WCQ, ws + OFF_BQ, ws + OFF_QF);
    k_gemm_exp<<<dim3(64, 4), 256, 0, stream>>>(x,            ws + OFF_WCK, ws + OFF_BK, ws + OFF_KF);
    k_gemm_exp<<<dim3(64, 4), 256, 0, stream>>>(ws + OFF_VC,  ws + OFF_WCV, ws + OFF_BV, ws + OFF_VF);
    k_kv_outer<<<dim3(16, 8), 256, 0, stream>>>(ws);
    k_reduce<<<130, 256, 0, stream>>>(ws);
    k_out<<<dim3(64, 8), 256, 0, stream>>>(ws, out);
}

// Round 2
// 146.963 us; speedup vs baseline: 1.1628x; 1.1628x over previous
//
#include <hip/hip_runtime.h>
#include <math.h>

#define EPS_F 1e-6f

// ---- workspace layout (float offsets), total ~3.34M floats (~13.4 MB) ----
#define OFF_WCQ 0                            // folded q weights [256][256]
#define OFF_WCK (OFF_WCQ + 65536)            // folded k weights [256][256]
#define OFF_BV  (OFF_WCK + 65536)            // folded v bias [256]
#define OFF_VC  (OFF_BV + 256)               // dwconv output [256][4096]
#define OFF_PS  (OFF_VC + 256*4096)          // partial Sm [8 h][64 chunk][64][64]
#define OFF_PSV (OFF_PS + 8*64*4096)         // partial sv [8 h][64 chunk][64]
#define OFF_SM  (OFF_PSV + 8*64*64)          // Sm [8][64*64]
#define OFF_SV  (OFF_SM + 8*4096)            // sv [8][64]

// Fold hedgehog linear into 1x1x1 conv: Wcq[h*64+e,c] = sum_d Wmq[e,d]*Wq[h*64+d,c]
// (same for k). V path stays per-head (Wmv used directly); fold bv into bveff.
__global__ __launch_bounds__(256) void k_combine(
    const float* __restrict__ Wq, const float* __restrict__ Wk,
    const float* __restrict__ Wmq, const float* __restrict__ Wmk,
    const float* __restrict__ Wmv, const float* __restrict__ bmv,
    const float* __restrict__ bv, float* __restrict__ ws)
{
    int row = blockIdx.x;        // h*64+e
    int c = threadIdx.x;
    int h = row >> 6, e = row & 63;
    float aq = 0.f, ak = 0.f;
    for (int d = 0; d < 64; ++d) {
        float mq = Wmq[e*64 + d];
        float mk = Wmk[e*64 + d];
        int src = (h*64 + d)*256 + c;
        aq = fmaf(mq, Wq[src], aq);
        ak = fmaf(mk, Wk[src], ak);
    }
    ws[OFF_WCQ + row*256 + c] = aq;
    ws[OFF_WCK + row*256 + c] = ak;
    if (c == 0) {
        float av = 0.f;
        for (int d = 0; d < 64; ++d) av = fmaf(Wmv[e*64 + d], bv[h*64 + d], av);
        ws[OFF_BV + row] = av + bmv[e];
    }
}

// depthwise 3x3x3 conv, zero pad, bias folded downstream
__global__ __launch_bounds__(256) void k_dwconv(
    const float* __restrict__ x, const float* __restrict__ Wv, float* __restrict__ vc)
{
    int c = blockIdx.y;
    int n = blockIdx.x * 256 + threadIdx.x;
    int z = n >> 8, y = (n >> 4) & 15, xx = n & 15;
    const float* xc = x + c * 4096;
    const float* wc = Wv + c * 27;
    float acc = 0.f;
    #pragma unroll
    for (int kz = 0; kz < 3; ++kz) {
        int zz = z + kz - 1;
        if (zz < 0 || zz > 15) continue;
        #pragma unroll
        for (int ky = 0; ky < 3; ++ky) {
            int yy = y + ky - 1;
            if (yy < 0 || yy > 15) continue;
            #pragma unroll
            for (int kx = 0; kx < 3; ++kx) {
                int xv = xx + kx - 1;
                if (xv < 0 || xv > 15) continue;
                acc = fmaf(wc[(kz*3 + ky)*3 + kx], xc[(zz << 8) + (yy << 4) + xv], acc);
            }
        }
    }
    vc[c*4096 + n] = acc;
}

// Per (hb in 0..3, chunk of 64 tokens):
//   Ak = Wck[hb]·X_chunk (K=256), Av = Wmv·VC[hb]_chunk (K=64)
//   kf± = exp(±(Ak+bmk)), vf± = exp(±(Av+bveff)) -> LDS
//   partial Sm[h=hb] += kf+ ⊗ vf+, Sm[hb+4] += kf- ⊗ vf-, partial sv likewise.
__global__ __launch_bounds__(256, 1) void k_kv_fused(
    const float* __restrict__ X, const float* __restrict__ bmk,
    const float* __restrict__ Wmv, float* __restrict__ ws)
{
    __shared__ float smem[16384];   // 64 KB
    float (*Xs)[64]  = (float(*)[64])smem;           // phase 1: 4096
    float (*Ws)[68]  = (float(*)[68])(smem + 4096);  // phase 1: 4352
    float (*kfp)[64] = (float(*)[64])smem;           // phase 2/3
    float (*kfm)[64] = (float(*)[64])(smem + 4096);
    float (*vfp)[64] = (float(*)[64])(smem + 8192);
    float (*vfm)[64] = (float(*)[64])(smem + 12288);

    int t = threadIdx.x;
    int chunk = blockIdx.x;       // 0..63
    int hb = blockIdx.y;          // 0..3
    int n0 = chunk * 64;
    int lc = t >> 6, ln = t & 63;
    int e4 = (t & 15) * 4;        // phase-1 e / phase-3 a
    int n4 = (t >> 4) * 4;        // phase-1 n / phase-3 f

    float accK[4][4], accV[4][4];
    #pragma unroll
    for (int i = 0; i < 4; ++i)
        #pragma unroll
        for (int j = 0; j < 4; ++j) { accK[i][j] = 0.f; accV[i][j] = 0.f; }

    // ---- phase 1: K-projection GEMM, K=256 ----
    const float* Wck = ws + OFF_WCK;
    for (int c0 = 0; c0 < 256; c0 += 64) {
        #pragma unroll
        for (int i = 0; i < 16; ++i)
            Xs[lc*16 + i][ln] = X[(size_t)(c0 + lc*16 + i)*4096 + n0 + ln];
        #pragma unroll
        for (int i = 0; i < 16; ++i)
            Ws[ln][lc*16 + i] = Wck[(size_t)(hb*64 + lc*16 + i)*256 + c0 + ln];
        __syncthreads();
        #pragma unroll 4
        for (int c = 0; c < 64; ++c) {
            float4 xv4 = *(const float4*)&Xs[c][n4];
            float4 wv4 = *(const float4*)&Ws[c][e4];
            float xv[4] = {xv4.x, xv4.y, xv4.z, xv4.w};
            float wv[4] = {wv4.x, wv4.y, wv4.z, wv4.w};
            #pragma unroll
            for (int ii = 0; ii < 4; ++ii)
                #pragma unroll
                for (int jj = 0; jj < 4; ++jj)
                    accK[ii][jj] = fmaf(xv[ii], wv[jj], accK[ii][jj]);
        }
        __syncthreads();
    }

    // ---- phase 1b: V-projection GEMM, K=64 (block-diagonal) ----
    const float* vcb = ws + OFF_VC + (size_t)hb*64*4096;
    #pragma unroll
    for (int i = 0; i < 16; ++i)
        Xs[lc*16 + i][ln] = vcb[(size_t)(lc*16 + i)*4096 + n0 + ln];
    #pragma unroll
    for (int i = 0; i < 16; ++i) { int idx = i*256 + t; Ws[idx & 63][idx >> 6] = Wmv[idx]; }
    __syncthreads();
    #pragma unroll 4
    for (int d = 0; d < 64; ++d) {
        float4 xv4 = *(const float4*)&Xs[d][n4];
        float4 wv4 = *(const float4*)&Ws[d][e4];
        float xv[4] = {xv4.x, xv4.y, xv4.z, xv4.w};
        float wv[4] = {wv4.x, wv4.y, wv4.z, wv4.w};
        #pragma unroll
        for (int ii = 0; ii < 4; ++ii)
            #pragma unroll
            for (int jj = 0; jj < 4; ++jj)
                accV[ii][jj] = fmaf(xv[ii], wv[jj], accV[ii][jj]);
    }
    __syncthreads();

    // ---- phase 2: bias + exp± into LDS [n][a] ----
    float bk[4], bvv[4];
    #pragma unroll
    for (int j = 0; j < 4; ++j) { bk[j] = bmk[e4 + j]; bvv[j] = ws[OFF_BV + hb*64 + e4 + j]; }
    #pragma unroll
    for (int ii = 0; ii < 4; ++ii) {
        float pk[4], mk_[4], pv[4], mv[4];
        #pragma unroll
        for (int jj = 0; jj < 4; ++jj) {
            float a = accK[ii][jj] + bk[jj];
            pk[jj] = __expf(a);  mk_[jj] = __expf(-a);
            float b = accV[ii][jj] + bvv[jj];
            pv[jj] = __expf(b);  mv[jj] = __expf(-b);
        }
        *(float4*)&kfp[n4 + ii][e4] = make_float4(pk[0], pk[1], pk[2], pk[3]);
        *(float4*)&kfm[n4 + ii][e4] = make_float4(mk_[0], mk_[1], mk_[2], mk_[3]);
        *(float4*)&vfp[n4 + ii][e4] = make_float4(pv[0], pv[1], pv[2], pv[3]);
        *(float4*)&vfm[n4 + ii][e4] = make_float4(mv[0], mv[1], mv[2], mv[3]);
    }
    __syncthreads();

    // ---- phase 3: outer products over the 64 tokens ----
    float aSp[4][4], aSm[4][4], svp[4], svm[4];
    #pragma unroll
    for (int i = 0; i < 4; ++i) {
        svp[i] = 0.f; svm[i] = 0.f;
        #pragma unroll
        for (int j = 0; j < 4; ++j) { aSp[i][j] = 0.f; aSm[i][j] = 0.f; }
    }
    int a4 = e4, f4 = n4;
    #pragma unroll 2
    for (int n = 0; n < 64; ++n) {
        float4 kp4 = *(const float4*)&kfp[n][a4];
        float4 km4 = *(const float4*)&kfm[n][a4];
        float4 vp4 = *(const float4*)&vfp[n][f4];
        float4 vm4 = *(const float4*)&vfm[n][f4];
        float kp[4] = {kp4.x, kp4.y, kp4.z, kp4.w};
        float km[4] = {km4.x, km4.y, km4.z, km4.w};
        float vp[4] = {vp4.x, vp4.y, vp4.z, vp4.w};
        float vm[4] = {vm4.x, vm4.y, vm4.z, vm4.w};
        #pragma unroll
        for (int ai = 0; ai < 4; ++ai) {
            svp[ai] += kp[ai];  svm[ai] += km[ai];
            #pragma unroll
            for (int fi = 0; fi < 4; ++fi) {
                aSp[ai][fi] = fmaf(kp[ai], vp[fi], aSp[ai][fi]);
                aSm[ai][fi] = fmaf(km[ai], vm[fi], aSm[ai][fi]);
            }
        }
    }
    float* pSp = ws + OFF_PS + (size_t)(hb*64 + chunk)*4096;
    float* pSm = ws + OFF_PS + (size_t)((hb + 4)*64 + chunk)*4096;
    #pragma unroll
    for (int ai = 0; ai < 4; ++ai) {
        *(float4*)&pSp[(a4 + ai)*64 + f4] = make_float4(aSp[ai][0], aSp[ai][1], aSp[ai][2], aSp[ai][3]);
        *(float4*)&pSm[(a4 + ai)*64 + f4] = make_float4(aSm[ai][0], aSm[ai][1], aSm[ai][2], aSm[ai][3]);
    }
    if (t < 16) {
        float* pvp = ws + OFF_PSV + (size_t)(hb*64 + chunk)*64;
        float* pvm = ws + OFF_PSV + (size_t)((hb + 4)*64 + chunk)*64;
        *(float4*)&pvp[a4] = make_float4(svp[0], svp[1], svp[2], svp[3]);
        *(float4*)&pvm[a4] = make_float4(svm[0], svm[1], svm[2], svm[3]);
    }
}

__global__ __launch_bounds__(256) void k_reduce(float* __restrict__ ws)
{
    int idx = blockIdx.x*256 + threadIdx.x;
    if (idx < 8*4096) {
        int h = idx >> 12, r = idx & 4095;
        float s = 0.f;
        #pragma unroll 16
        for (int c = 0; c < 64; ++c) s += ws[OFF_PS + (size_t)(h*64 + c)*4096 + r];
        ws[OFF_SM + idx] = s;
    } else if (idx < 8*4096 + 512) {
        int j = idx - 8*4096;
        int h = j >> 6, e = j & 63;
        float s = 0.f;
        #pragma unroll 16
        for (int c = 0; c < 64; ++c) s += ws[OFF_PSV + (size_t)(h*64 + c)*64 + e];
        ws[OFF_SV + j] = s;
    }
}

// Per (hb, chunk): Aq GEMM (K=256) -> qf± in LDS (transposed [a][n]) ->
// out[h] = (qf·Sm[h]) / (qf·sv[h] + eps) for h=hb (plus) and hb+4 (minus).
__global__ __launch_bounds__(256, 1) void k_q_out(
    const float* __restrict__ X, const float* __restrict__ bmq,
    const float* __restrict__ ws, float* __restrict__ out)
{
    __shared__ float smem[12352];
    float (*Xs)[64]   = (float(*)[64])smem;           // phase 1
    float (*Wsh)[68]  = (float(*)[68])(smem + 4096);  // phase 1
    float (*qfTp)[64] = (float(*)[64])smem;           // [a][n]
    float (*qfTm)[64] = (float(*)[64])(smem + 4096);
    float (*Sms)[64]  = (float(*)[64])(smem + 8192);
    float* svs        = smem + 12288;

    int t = threadIdx.x;
    int chunk = blockIdx.x;
    int hb = blockIdx.y;
    int n0 = chunk * 64;
    int lc = t >> 6, ln = t & 63;
    int a4_1 = (t & 15) * 4;      // phase-1 e(=a)
    int n4_1 = (t >> 4) * 4;      // phase-1 n

    float accQ[4][4];
    #pragma unroll
    for (int i = 0; i < 4; ++i)
        #pragma unroll
        for (int j = 0; j < 4; ++j) accQ[i][j] = 0.f;

    const float* Wcq = ws + OFF_WCQ;
    for (int c0 = 0; c0 < 256; c0 += 64) {
        #pragma unroll
        for (int i = 0; i < 16; ++i)
            Xs[lc*16 + i][ln] = X[(size_t)(c0 + lc*16 + i)*4096 + n0 + ln];
        #pragma unroll
        for (int i = 0; i < 16; ++i)
            Wsh[ln][lc*16 + i] = Wcq[(size_t)(hb*64 + lc*16 + i)*256 + c0 + ln];
        __syncthreads();
        #pragma unroll 4
        for (int c = 0; c < 64; ++c) {
            float4 xv4 = *(const float4*)&Xs[c][n4_1];
            float4 wv4 = *(const float4*)&Wsh[c][a4_1];
            float xv[4] = {xv4.x, xv4.y, xv4.z, xv4.w};
            float wv[4] = {wv4.x, wv4.y, wv4.z, wv4.w};
            #pragma unroll
            for (int ii = 0; ii < 4; ++ii)
                #pragma unroll
                for (int jj = 0; jj < 4; ++jj)
                    accQ[ii][jj] = fmaf(xv[ii], wv[jj], accQ[ii][jj]);
        }
        __syncthreads();
    }

    // phase 2: exp± into transposed LDS [a][n] (float4 along n)
    #pragma unroll
    for (int jj = 0; jj < 4; ++jj) {
        float b = bmq[a4_1 + jj];
        float v0 = accQ[0][jj] + b, v1 = accQ[1][jj] + b,
              v2 = accQ[2][jj] + b, v3 = accQ[3][jj] + b;
        *(float4*)&qfTp[a4_1 + jj][n4_1] =
            make_float4(__expf(v0), __expf(v1), __expf(v2), __expf(v3));
        *(float4*)&qfTm[a4_1 + jj][n4_1] =
            make_float4(__expf(-v0), __expf(-v1), __expf(-v2), __expf(-v3));
    }

    int n4 = (t & 15) * 4;        // phase-3 n (coalesced store)
    int e4 = (t >> 4) * 4;        // phase-3 e
    for (int s = 0; s < 2; ++s) {
        int h = hb + 4*s;
        __syncthreads();          // prior-phase LDS reads done before Sm overwrite
        const float* Smg = ws + OFF_SM + (size_t)h*4096;
        #pragma unroll
        for (int i = 0; i < 16; ++i) { int idx = i*256 + t; Sms[idx >> 6][idx & 63] = Smg[idx]; }
        if (t < 64) svs[t] = ws[OFF_SV + h*64 + t];
        __syncthreads();

        const float (*qf)[64] = s ? (const float(*)[64])qfTm : (const float(*)[64])qfTp;
        float acc[4][4];          // [e][n]
        float den[4] = {0.f, 0.f, 0.f, 0.f};
        #pragma unroll
        for (int i = 0; i < 4; ++i)
            #pragma unroll
            for (int j = 0; j < 4; ++j) acc[i][j] = 0.f;
        #pragma unroll 4
        for (int a = 0; a < 64; ++a) {
            float4 qv4 = *(const float4*)&qf[a][n4];
            float4 sm4 = *(const float4*)&Sms[a][e4];
            float qv[4] = {qv4.x, qv4.y, qv4.z, qv4.w};
            float sm[4] = {sm4.x, sm4.y, sm4.z, sm4.w};
            float sva = svs[a];
            #pragma unroll
            for (int nj = 0; nj < 4; ++nj) {
                den[nj] = fmaf(qv[nj], sva, den[nj]);
                #pragma unroll
                for (int ei = 0; ei < 4; ++ei)
                    acc[ei][nj] = fmaf(sm[ei], qv[nj], acc[ei][nj]);
            }
        }
        float r[4];
        #pragma unroll
        for (int nj = 0; nj < 4; ++nj) r[nj] = 1.f / (den[nj] + EPS_F);
        #pragma unroll
        for (int ei = 0; ei < 4; ++ei)
            *(float4*)&out[(size_t)(h*64 + e4 + ei)*4096 + n0 + n4] =
                make_float4(acc[ei][0]*r[0], acc[ei][1]*r[1], acc[ei][2]*r[2], acc[ei][3]*r[3]);
    }
}

extern "C" void kernel_launch(void* const* d_in, const int* in_sizes, int n_in,
                              void* d_out, int out_size, void* d_ws, size_t ws_size,
                              hipStream_t stream) {
    const float* x   = (const float*)d_in[0];
    const float* Wq  = (const float*)d_in[1];
    const float* Wk  = (const float*)d_in[2];
    const float* Wv  = (const float*)d_in[3];
    const float* bv  = (const float*)d_in[4];
    const float* Wmq = (const float*)d_in[5];
    const float* bmq = (const float*)d_in[6];
    const float* Wmk = (const float*)d_in[7];
    const float* bmk = (const float*)d_in[8];
    const float* Wmv = (const float*)d_in[9];
    const float* bmv = (const float*)d_in[10];
    float* out = (float*)d_out;
    float* ws  = (float*)d_ws;

    k_combine<<<256, 256, 0, stream>>>(Wq, Wk, Wmq, Wmk, Wmv, bmv, bv, ws);
    k_dwconv<<<dim3(16, 256), 256, 0, stream>>>(x, Wv, ws + OFF_VC);
    k_kv_fused<<<dim3(64, 4), 256, 0, stream>>>(x, bmk, Wmv, ws);
    k_reduce<<<130, 256, 0, stream>>>(ws);
    k_q_out<<<dim3(64, 4), 256, 0, stream>>>(x, bmq, ws, out);
}